// Round 2
// baseline (325.430 us; speedup 1.0000x reference)
//
#include <hip/hip_runtime.h>
#include <hip/hip_bf16.h>
#include <math.h>

typedef __hip_bfloat16 bf16;

#define B 32
#define V 64
#define F 128
#define NL 128
#define H 8
#define DH 16
#define T_PAST 20
#define LEN_PRED 30

// ---- canonical f32 input layout (element offsets into fin) ----
#define OFF_INP   0
#define OFF_LANES 81920
#define OFF_POS   344064
#define OFF_EMBW  348160
#define OFF_EMBB  348928
#define OFF_WQP   349056
#define OFF_WKLP  365440
#define OFF_WVLP  373632
#define OFF_WCP   381824
#define OFF_WKF   398208
#define OFF_WQSA  414592
#define OFF_WVF   430976
#define OFF_WCSA  447360
#define OFF_WKLF  463744
#define OFF_WVLF  471936
#define OFF_WQLA  480128
#define OFF_WCLA  496512
#define OFF_W1    512896
#define OFF_B1    529280
#define OFF_W2    529408
#define OFF_B2    545792
#define OFF_WO    545920
#define OFF_BO    550528

struct InPtrs { const void* p[23]; };

// ---------------- K0a: detect input dtype (f32 vs bf16) ----------------
// f32 data read as u16 pairs: low halves are mantissa bits -> wild exponents.
// bf16 N(0,1) data: exponent always near 127.
__global__ void k_detect(const void* lanesraw, int* flag) {
    const unsigned short* u = (const unsigned short*)lanesraw;
    int wild = 0;
    for (int i = 0; i < 256; i++) {
        int e = (u[i] >> 7) & 0xFF;
        if (e != 0 && (e < 90 || e > 164)) wild++;
    }
    *flag = (wild >= 32) ? 1 : 0;
}

// ---------------- K0b: convert all inputs to canonical f32 ----------------
__global__ void k_convert(InPtrs ptrs, const int* flag, float* fin) {
    const int sz[23] = {81920,262144,4096,768,128,16384,8192,8192,16384,16384,
                        16384,16384,16384,8192,8192,16384,16384,16384,128,16384,
                        128,4608,36};
    const int off[23] = {OFF_INP,OFF_LANES,OFF_POS,OFF_EMBW,OFF_EMBB,OFF_WQP,
                         OFF_WKLP,OFF_WVLP,OFF_WCP,OFF_WKF,OFF_WQSA,OFF_WVF,
                         OFF_WCSA,OFF_WKLF,OFF_WVLF,OFF_WQLA,OFF_WCLA,OFF_W1,
                         OFF_B1,OFF_W2,OFF_B2,OFF_WO,OFF_BO};
    int seg = blockIdx.y;
    int n = sz[seg];
    int i = blockIdx.x * 256 + threadIdx.x;
    if (i >= n) return;
    float v;
    if (*flag) v = ((const float*)ptrs.p[seg])[i];
    else       v = __bfloat162float(((const bf16*)ptrs.p[seg])[i]);
    fin[off[seg] + i] = v;
}

// ---------------- K1: embedding conv @ last timestep -> feat [B,V,128] ----------------
__global__ void k_feat(const float* __restrict__ fin, float* __restrict__ feat) {
    const float* inp = fin + OFF_INP;
    const float* ew  = fin + OFF_EMBW;
    const float* eb  = fin + OFF_EMBB;
    int bv = blockIdx.x;            // b*64+v
    int b = bv >> 6, v = bv & 63;
    int o = threadIdx.x;            // 0..127
    // inputs [B,2,V,20]; kernel (1,3), pad 1: out[19] = w[*,0]*in[18] + w[*,1]*in[19] (+pad)
    float in00 = inp[((b * 2 + 0) * V + v) * T_PAST + 18];
    float in01 = inp[((b * 2 + 0) * V + v) * T_PAST + 19];
    float in10 = inp[((b * 2 + 1) * V + v) * T_PAST + 18];
    float in11 = inp[((b * 2 + 1) * V + v) * T_PAST + 19];
    float w00 = ew[(o * 2 + 0) * 3 + 0], w01 = ew[(o * 2 + 0) * 3 + 1];
    float w10 = ew[(o * 2 + 1) * 3 + 0], w11 = ew[(o * 2 + 1) * 3 + 1];
    feat[bv * F + o] = eb[o] + in00 * w00 + in01 * w01 + in10 * w10 + in11 * w11;
}

// ---------------- K2: lane projections (4 mats) -> [B,128,128] each ----------------
__global__ void k_laneproj(const float* __restrict__ fin,
                           float* __restrict__ kp, float* __restrict__ vp,
                           float* __restrict__ klf, float* __restrict__ vlf) {
    const float* lanes = fin + OFF_LANES;
    const float* wkp = fin + OFF_WKLP; const float* wvp = fin + OFF_WVLP;
    const float* wkf = fin + OFF_WKLF; const float* wvf = fin + OFF_WVLF;
    int bl = blockIdx.x;            // b*128 + lane
    int o = threadIdx.x;            // 0..127
    __shared__ float ln[64];
    if (o < 64) ln[o] = lanes[bl * 64 + o];
    __syncthreads();
    float a0 = 0.f, a1 = 0.f, a2 = 0.f, a3 = 0.f;
    for (int k = 0; k < 64; k++) {
        float x = ln[k];
        a0 += x * wkp[o * 64 + k];
        a1 += x * wvp[o * 64 + k];
        a2 += x * wkf[o * 64 + k];
        a3 += x * wvf[o * 64 + k];
    }
    kp[bl * F + o] = a0; vp[bl * F + o] = a1;
    klf[bl * F + o] = a2; vlf[bl * F + o] = a3;
}

// ---------------- K3: LaneAttentionPast, block per (b,v) ----------------
__global__ void k_lap(const float* __restrict__ fin,
                      const float* __restrict__ kp, const float* __restrict__ vp,
                      float* __restrict__ feat) {
    const float* wq = fin + OFF_WQP;
    const float* wc = fin + OFF_WCP;
    int bv = blockIdx.x; int b = bv >> 6;
    int t = threadIdx.x;            // 0..127
    __shared__ float fr[F], q[F], s[H][NL], osum[H], oatt[F];
    fr[t] = feat[bv * F + t];
    __syncthreads();
    float acc = 0.f;
    for (int k = 0; k < F; k++) acc += fr[k] * wq[t * F + k];
    q[t] = acc;
    __syncthreads();
    const float* kpb = kp + b * NL * F;
    for (int j = 0; j < 8; j++) {
        int pi = t + 128 * j; int h = pi >> 7, l = pi & 127;
        const float* kr = kpb + l * F + h * DH;
        const float* qh = q + h * DH;
        float sc = 0.f;
        for (int d = 0; d < DH; d++) sc += qh[d] * kr[d];
        s[h][l] = sc * 0.25f;
    }
    __syncthreads();
    int h = t >> 4, d = t & 15;     // aligned 16-lane groups per head
    float m = -1e30f;
    for (int k = 0; k < 8; k++) m = fmaxf(m, s[h][d + 16 * k]);
    for (int off = 1; off < 16; off <<= 1) m = fmaxf(m, __shfl_xor(m, off, 64));
    float sum = 0.f;
    for (int k = 0; k < 8; k++) { float e = __expf(s[h][d + 16 * k] - m); s[h][d + 16 * k] = e; sum += e; }
    for (int off = 1; off < 16; off <<= 1) sum += __shfl_xor(sum, off, 64);
    if (d == 0) osum[h] = sum;
    __syncthreads();
    const float* vpb = vp + b * NL * F;
    float oa = 0.f;
    for (int l = 0; l < NL; l++) oa += s[h][l] * vpb[l * F + t];
    oatt[t] = oa / osum[h];
    __syncthreads();
    float r = 0.f;
    for (int k = 0; k < F; k++) r += oatt[k] * wc[t * F + k];
    feat[bv * F + t] = r + fr[t];
}

// ---------------- K4: SelfAttentionFut (single timestep), block per (b,h) ----------------
__global__ void k_saf(const float* __restrict__ fin, const float* __restrict__ feat,
                      float* __restrict__ osa) {
    const float* wk = fin + OFF_WKF;
    const float* wq = fin + OFF_WQSA;
    const float* wv = fin + OFF_WVF;
    int bh = blockIdx.x; int b = bh >> 3, h = bh & 7;
    int t = threadIdx.x;            // 0..255
    __shared__ float x[V][F];
    __shared__ float qh[V][DH], kh[V][DH], vh[V][DH];
    __shared__ float s[V][V];
    __shared__ float rsum[V];
    const float* fb = feat + b * V * F;
    for (int i = t; i < V * F; i += 256) x[i >> 7][i & 127] = fb[i];
    __syncthreads();
    for (int i = t; i < V * DH; i += 256) {
        int v = i >> 4, d = i & 15;
        const float* wqr = wq + (h * DH + d) * F;
        const float* wkr = wk + (h * DH + d) * F;
        const float* wvr = wv + (h * DH + d) * F;
        float aq = 0.f, ak = 0.f, av = 0.f;
        for (int k = 0; k < F; k++) {
            float xv = x[v][k];
            aq += xv * wqr[k]; ak += xv * wkr[k]; av += xv * wvr[k];
        }
        qh[v][d] = aq; kh[v][d] = ak; vh[v][d] = av;
    }
    __syncthreads();
    for (int i = t; i < V * V; i += 256) {
        int vq = i >> 6, vk = i & 63;
        float sc = 0.f;
        for (int d = 0; d < DH; d++) sc += qh[vq][d] * kh[vk][d];
        s[vq][vk] = sc * 0.25f;
    }
    __syncthreads();
    {   // softmax rows, aligned 4-lane groups
        int vq = t >> 2, j = t & 3;
        float m = -1e30f;
        for (int k = j; k < V; k += 4) m = fmaxf(m, s[vq][k]);
        for (int off = 1; off < 4; off <<= 1) m = fmaxf(m, __shfl_xor(m, off, 64));
        float sum = 0.f;
        for (int k = j; k < V; k += 4) { float e = __expf(s[vq][k] - m); s[vq][k] = e; sum += e; }
        for (int off = 1; off < 4; off <<= 1) sum += __shfl_xor(sum, off, 64);
        if (j == 0) rsum[vq] = sum;
    }
    __syncthreads();
    float* ob = osa + b * V * F;
    for (int i = t; i < V * DH; i += 256) {
        int vq = i >> 4, d = i & 15;
        float a = 0.f;
        for (int vk = 0; vk < V; vk++) a += s[vq][vk] * vh[vk][d];
        ob[vq * F + h * DH + d] = a / rsum[vq];
    }
}

// ---------------- K5: proj + residual (feat += o @ wc^T) ----------------
__global__ void k_proj_res(const float* __restrict__ wc, const float* __restrict__ oin,
                           float* __restrict__ feat) {
    int bv = blockIdx.x; int t = threadIdx.x;
    __shared__ float orow[F];
    orow[t] = oin[bv * F + t];
    __syncthreads();
    float a = 0.f;
    for (int k = 0; k < F; k++) a += orow[k] * wc[t * F + k];
    feat[bv * F + t] += a;
}

// ---------------- K6: LaneAttentionFut, block per (b,h) ----------------
__global__ void k_laf(const float* __restrict__ fin, const float* __restrict__ klf,
                      const float* __restrict__ vlf, const float* __restrict__ feat,
                      float* __restrict__ ola) {
    const float* wq = fin + OFF_WQLA;
    int bh = blockIdx.x; int b = bh >> 3, h = bh & 7;
    int t = threadIdx.x;            // 0..255
    __shared__ float x[V][F];
    __shared__ float qh[V][DH];
    __shared__ float kh[NL][DH], vh[NL][DH];
    __shared__ float s[V][NL];
    __shared__ float rsum[V];
    const float* fb = feat + b * V * F;
    for (int i = t; i < V * F; i += 256) x[i >> 7][i & 127] = fb[i];
    const float* kb = klf + b * NL * F;
    const float* vb = vlf + b * NL * F;
    for (int i = t; i < NL * DH; i += 256) {
        int l = i >> 4, d = i & 15;
        kh[l][d] = kb[l * F + h * DH + d];
        vh[l][d] = vb[l * F + h * DH + d];
    }
    __syncthreads();
    for (int i = t; i < V * DH; i += 256) {
        int v = i >> 4, d = i & 15;
        const float* wr = wq + (h * DH + d) * F;
        float a = 0.f;
        for (int k = 0; k < F; k++) a += x[v][k] * wr[k];
        qh[v][d] = a;
    }
    __syncthreads();
    for (int i = t; i < V * NL; i += 256) {
        int vq = i >> 7, l = i & 127;
        float a = 0.f;
        for (int d = 0; d < DH; d++) a += qh[vq][d] * kh[l][d];
        s[vq][l] = a * 0.25f;
    }
    __syncthreads();
    {
        int vq = t >> 2, j = t & 3;
        float m = -1e30f;
        for (int k = j; k < NL; k += 4) m = fmaxf(m, s[vq][k]);
        for (int off = 1; off < 4; off <<= 1) m = fmaxf(m, __shfl_xor(m, off, 64));
        float sum = 0.f;
        for (int k = j; k < NL; k += 4) { float e = __expf(s[vq][k] - m); s[vq][k] = e; sum += e; }
        for (int off = 1; off < 4; off <<= 1) sum += __shfl_xor(sum, off, 64);
        if (j == 0) rsum[vq] = sum;
    }
    __syncthreads();
    float* ob = ola + b * V * F;
    for (int i = t; i < V * DH; i += 256) {
        int vq = i >> 4, d = i & 15;
        float a = 0.f;
        for (int l = 0; l < NL; l++) a += s[vq][l] * vh[l][d];
        ob[vq * F + h * DH + d] = a / rsum[vq];
    }
}

// ---------------- K7: final proj + residual + MLP + output activation -> act [B,V,36] ----------------
__global__ void k_out(const float* __restrict__ fin, const float* __restrict__ ola,
                      const float* __restrict__ feat, float* __restrict__ act) {
    const float* wcla = fin + OFF_WCLA;
    const float* w1 = fin + OFF_W1; const float* b1 = fin + OFF_B1;
    const float* w2 = fin + OFF_W2; const float* b2 = fin + OFF_B2;
    const float* wo = fin + OFF_WO; const float* bo = fin + OFF_BO;
    const float* pos = fin + OFF_POS;
    int bv = blockIdx.x; int t = threadIdx.x;
    __shared__ float orow[F], h3[F], z1[F], z2[F], z3[36];
    orow[t] = ola[bv * F + t];
    __syncthreads();
    float a = 0.f;
    for (int k = 0; k < F; k++) a += orow[k] * wcla[t * F + k];
    h3[t] = a + feat[bv * F + t];
    __syncthreads();
    a = b1[t];
    for (int k = 0; k < F; k++) a += h3[k] * w1[t * F + k];
    z1[t] = fmaxf(a, 0.f);
    __syncthreads();
    a = b2[t];
    for (int k = 0; k < F; k++) a += z1[k] * w2[t * F + k];
    z2[t] = fmaxf(a, 0.f);
    __syncthreads();
    if (t < 36) {
        a = bo[t];
        for (int k = 0; k < F; k++) a += z2[k] * wo[t * F + k];
        z3[t] = a;
    }
    __syncthreads();
    if (t < 36) {
        int c = t % 6;
        float xv = z3[t];
        float r;
        if (c == 0)      r = xv + pos[bv * 2 + 0];
        else if (c == 1) r = xv + pos[bv * 2 + 1];
        else if (c == 2 || c == 3) r = __expf(0.5f * xv);
        else if (c == 4) r = tanhf(xv);
        else {
            const float inv = 0.4082482904638631f;  // 1/sqrt(6)
            float m = -1e30f;
            for (int pp = 0; pp < 6; pp++) m = fmaxf(m, z3[pp * 6 + 5] * inv);
            float sum = 0.f;
            for (int pp = 0; pp < 6; pp++) sum += __expf(z3[pp * 6 + 5] * inv - m);
            r = __expf(xv * inv - m) / sum;
        }
        act[bv * 36 + t] = r;
    }
}

// ---------------- K8: broadcast over LEN_PRED, dtype per flag ----------------
__global__ void k_bcast(const float* __restrict__ act, void* __restrict__ out,
                        const int* __restrict__ flag, int total) {
    int i = blockIdx.x * 256 + threadIdx.x;
    if (i < total) {
        int j = i % (B * V * 36);
        float v = act[j];
        if (*flag) ((float*)out)[i] = v;
        else       ((bf16*)out)[i] = __float2bfloat16(v);
    }
}

extern "C" void kernel_launch(void* const* d_in, const int* in_sizes, int n_in,
                              void* d_out, int out_size, void* d_ws, size_t ws_size,
                              hipStream_t stream) {
    float* ws   = (float*)d_ws;
    float* fin  = ws;                    // 550564 f32 canonical inputs
    float* feat = ws + 550656;           // B*V*F = 262144
    float* osa  = ws + 812800;           // B*V*F
    float* kp   = ws + 1074944;          // B*NL*F = 524288
    float* vp   = ws + 1599232;
    float* klf  = ws + 2123520;
    float* vlf  = ws + 2647808;
    float* actb = ws + 3172096;          // B*V*36 = 73728
    int*   flag = (int*)(ws + 3245824);

    k_detect<<<1, 1, 0, stream>>>(d_in[1], flag);

    InPtrs ptrs;
    for (int i = 0; i < 23; i++) ptrs.p[i] = d_in[i];
    k_convert<<<dim3(1024, 23), 256, 0, stream>>>(ptrs, flag, fin);

    k_feat<<<B * V, 128, 0, stream>>>(fin, feat);
    k_laneproj<<<B * NL, 128, 0, stream>>>(fin, kp, vp, klf, vlf);
    k_lap<<<B * V, 128, 0, stream>>>(fin, kp, vp, feat);
    k_saf<<<B * H, 256, 0, stream>>>(fin, feat, osa);
    k_proj_res<<<B * V, 128, 0, stream>>>(fin + OFF_WCSA, osa, feat);
    k_laf<<<B * H, 256, 0, stream>>>(fin, klf, vlf, feat, osa);
    k_out<<<B * V, 128, 0, stream>>>(fin, osa, feat, actb);

    int total = LEN_PRED * B * V * 36;   // 2,211,840
    k_bcast<<<(total + 255) / 256, 256, 0, stream>>>(actb, d_out, flag, total);
}

// Round 3
// 183.509 us; speedup vs baseline: 1.7734x; 1.7734x over previous
//
#include <hip/hip_runtime.h>
#include <hip/hip_bf16.h>
#include <math.h>

typedef __hip_bfloat16 bf16;

#define B 32
#define V 64
#define F 128
#define NL 128
#define H 8
#define DH 16
#define LEN_PRED 30

// ---- f32 workspace layout (element offsets) ----
#define OFF_INP   0
#define OFF_LANES 81920
#define OFF_POS   344064
#define OFF_EMBW  348160
#define OFF_EMBB  348928
#define OFF_B1    349056
#define OFF_B2    349184
#define OFF_BO    349312
// transposed weights [in][out]
#define WQP_T     349440
#define WKLP_T    365824
#define WVLP_T    374016
#define WCP_T     382208
#define WKF_T     398592
#define WQSA_T    414976
#define WVF_T     431360
#define WCSA_T    447744
#define WKLF_T    464128
#define WVLF_T    472320
#define WQLA_T    480512
#define WCLA_T    496896
#define W1_T      513280
#define W2_T      529664
#define WO_T      546048
// intermediates
#define OFF_FEAT  550656
#define OFF_OSA   812800
#define OFF_KP    1074944
#define OFF_VP    1599232
#define OFF_KLF   2123520
#define OFF_VLF   2647808
#define OFF_FLAG  3172096

struct InPtrs { const void* p[23]; };

// ---------------- detect input dtype (f32 vs bf16), one wave ----------------
__global__ void k_detect(const void* lanesraw, int* flag) {
    const unsigned short* u = (const unsigned short*)lanesraw;
    int lane = threadIdx.x;            // 0..63
    int wild = 0;
    for (int i = 0; i < 4; i++) {
        int e = (u[lane * 4 + i] >> 7) & 0xFF;
        if (e != 0 && (e < 90 || e > 164)) wild++;
    }
    unsigned long long m = __ballot(wild > 0);
    if (lane == 0) *flag = (__popcll(m) >= 16) ? 1 : 0;
}

// ---------------- convert to f32; transpose weight matrices [O][K]->[K][O] ----------------
__global__ void k_prep(InPtrs ptrs, const int* __restrict__ flag, float* __restrict__ ws) {
    const int sz[23]   = {81920,262144,4096,768,128, 16384,8192,8192,16384,
                          16384,16384,16384,16384, 8192,8192,16384,16384,
                          16384,128,16384,128,4608,36};
    const int dsto[23] = {OFF_INP,OFF_LANES,OFF_POS,OFF_EMBW,OFF_EMBB,
                          WQP_T,WKLP_T,WVLP_T,WCP_T, WKF_T,WQSA_T,WVF_T,WCSA_T,
                          WKLF_T,WVLF_T,WQLA_T,WCLA_T, W1_T,OFF_B1,W2_T,OFF_B2,
                          WO_T,OFF_BO};
    const int Otab[23] = {0,0,0,0,0, 128,128,128,128, 128,128,128,128,
                          128,128,128,128, 128,0,128,0,36,0};
    const int Ktab[23] = {0,0,0,0,0, 128,64,64,128, 128,128,128,128,
                          64,64,128,128, 128,0,128,0,128,0};
    int seg = blockIdx.y;
    int n = sz[seg], O = Otab[seg], K = Ktab[seg];
    int fl = *flag;
    int t = threadIdx.x;
    if (O == 0) {                       // linear copy
        int i = blockIdx.x * 256 + t;
        if (i < n) {
            float v = fl ? ((const float*)ptrs.p[seg])[i]
                         : __bfloat162float(((const bf16*)ptrs.p[seg])[i]);
            ws[dsto[seg] + i] = v;
        }
        return;
    }
    if (blockIdx.x != 0) return;        // one block per matrix
    __shared__ float tile[128 * 129];
    int Kp = K + 1;
    for (int i = t; i < n; i += 256) {
        float v = fl ? ((const float*)ptrs.p[seg])[i]
                     : __bfloat162float(((const bf16*)ptrs.p[seg])[i]);
        int o = i / K, k = i - o * K;
        tile[o * Kp + k] = v;
    }
    __syncthreads();
    float* dst = ws + dsto[seg];
    for (int j = t; j < n; j += 256) {
        int k = j / O, o = j - k * O;
        dst[j] = tile[o * Kp + k];
    }
}

// ---------------- lane projections: [B*NL,64] x 4 transposed mats ----------------
__global__ void k_laneproj(const float* __restrict__ ws, float* __restrict__ wsw) {
    int bl = blockIdx.x;                // b*128 + l
    int o = threadIdx.x;                // 0..127
    __shared__ float ln[64];
    if (o < 64) ln[o] = ws[OFF_LANES + bl * 64 + o];
    __syncthreads();
    const float* wkp = ws + WKLP_T; const float* wvp = ws + WVLP_T;
    const float* wkf = ws + WKLF_T; const float* wvf = ws + WVLF_T;
    float a0 = 0.f, a1 = 0.f, a2 = 0.f, a3 = 0.f;
    for (int k = 0; k < 64; k++) {
        float x = ln[k];
        a0 += x * wkp[k * 128 + o];
        a1 += x * wvp[k * 128 + o];
        a2 += x * wkf[k * 128 + o];
        a3 += x * wvf[k * 128 + o];
    }
    wsw[OFF_KP  + bl * 128 + o] = a0;
    wsw[OFF_VP  + bl * 128 + o] = a1;
    wsw[OFF_KLF + bl * 128 + o] = a2;
    wsw[OFF_VLF + bl * 128 + o] = a3;
}

// ---------------- embedding feat + LaneAttentionPast, block per (b,v) ----------------
__global__ void k_lap(const float* __restrict__ ws, float* __restrict__ feat) {
    int bv = blockIdx.x; int b = bv >> 6, v = bv & 63;
    int t = threadIdx.x;                // 0..127
    __shared__ float ks[128 * 129];     // kp[b] staged, padded
    __shared__ float fr[128], q[128], s[8 * 128], osum[8], oatt[128];
    // phase 0: embedding conv at last timestep
    const float* inp = ws + OFF_INP;
    float in00 = inp[((b * 2 + 0) * 64 + v) * 20 + 18];
    float in01 = inp[((b * 2 + 0) * 64 + v) * 20 + 19];
    float in10 = inp[((b * 2 + 1) * 64 + v) * 20 + 18];
    float in11 = inp[((b * 2 + 1) * 64 + v) * 20 + 19];
    const float* ew = ws + OFF_EMBW;
    float f0 = ws[OFF_EMBB + t] + in00 * ew[t * 6 + 0] + in01 * ew[t * 6 + 1]
             + in10 * ew[t * 6 + 3] + in11 * ew[t * 6 + 4];
    fr[t] = f0;
    // stage kp[b]
    const float* kpb = ws + OFF_KP + b * NL * F;
    for (int i = t; i < NL * F; i += 128) ks[(i >> 7) * 129 + (i & 127)] = kpb[i];
    __syncthreads();
    // q projection (coalesced wT)
    const float* wqT = ws + WQP_T;
    float acc = 0.f;
    for (int k = 0; k < 128; k++) acc += fr[k] * wqT[k * 128 + t];
    q[t] = acc;
    __syncthreads();
    // scores s[h][l]
    int h = t >> 4, dlo = t & 15;
    for (int j = 0; j < 8; j++) {
        int l = dlo + 16 * j;
        const float* kr = ks + l * 129 + h * 16;
        const float* qh = q + h * 16;
        float sc = 0.f;
        for (int d = 0; d < 16; d++) sc += qh[d] * kr[d];
        s[h * 128 + l] = sc * 0.25f;
    }
    __syncthreads();
    // softmax per head, 16-lane groups
    float m = -1e30f;
    for (int k = 0; k < 8; k++) m = fmaxf(m, s[h * 128 + dlo + 16 * k]);
    for (int off = 1; off < 16; off <<= 1) m = fmaxf(m, __shfl_xor(m, off));
    float sum = 0.f;
    for (int k = 0; k < 8; k++) {
        float e = __expf(s[h * 128 + dlo + 16 * k] - m);
        s[h * 128 + dlo + 16 * k] = e; sum += e;
    }
    for (int off = 1; off < 16; off <<= 1) sum += __shfl_xor(sum, off);
    if (dlo == 0) osum[h] = sum;
    __syncthreads();
    // PV: vp stays global (coalesced over t)
    const float* vpb = ws + OFF_VP + b * NL * F;
    float oa = 0.f;
    for (int l = 0; l < NL; l++) oa += s[h * 128 + l] * vpb[l * F + t];
    oatt[t] = oa / osum[h];
    __syncthreads();
    // output proj + residual
    const float* wcT = ws + WCP_T;
    float r = 0.f;
    for (int k = 0; k < 128; k++) r += oatt[k] * wcT[k * 128 + t];
    feat[bv * F + t] = r + f0;
}

// ---------------- SelfAttentionFut, block per (b,h), 512 thr ----------------
__global__ __launch_bounds__(512) void k_saf(const float* __restrict__ ws,
                                             const float* __restrict__ feat,
                                             float* __restrict__ osa) {
    int bh = blockIdx.x; int b = bh >> 3, h = bh & 7;
    int t = threadIdx.x;                // 0..511
    __shared__ float xs[64 * 129];
    __shared__ float qh[64 * 17], kh[64 * 17], vh[64 * 17];
    __shared__ float s[64 * 65];
    __shared__ float rsum[64];
    const float* fb = feat + b * V * F;
    for (int i = t; i < V * F; i += 512) xs[(i >> 7) * 129 + (i & 127)] = fb[i];
    __syncthreads();
    const float* wkT = ws + WKF_T  + h * 16;
    const float* wqT = ws + WQSA_T + h * 16;
    const float* wvT = ws + WVF_T  + h * 16;
    for (int i = t; i < V * DH; i += 512) {
        int v = i >> 4, d = i & 15;
        const float* xr = xs + v * 129;
        float aq = 0.f, ak = 0.f, av = 0.f;
        for (int k = 0; k < 128; k++) {
            float xv = xr[k];
            aq += xv * wqT[k * 128 + d];
            ak += xv * wkT[k * 128 + d];
            av += xv * wvT[k * 128 + d];
        }
        qh[v * 17 + d] = aq; kh[v * 17 + d] = ak; vh[v * 17 + d] = av;
    }
    __syncthreads();
    for (int i = t; i < V * V; i += 512) {
        int vq = i >> 6, vk = i & 63;
        const float* qr = qh + vq * 17; const float* kr = kh + vk * 17;
        float sc = 0.f;
        for (int d = 0; d < 16; d++) sc += qr[d] * kr[d];
        s[vq * 65 + vk] = sc * 0.25f;
    }
    __syncthreads();
    {
        int vq = t >> 3, j = t & 7;     // 8 lanes per row
        float m = -1e30f;
        for (int k = j; k < V; k += 8) m = fmaxf(m, s[vq * 65 + k]);
        for (int off = 1; off < 8; off <<= 1) m = fmaxf(m, __shfl_xor(m, off));
        float sum = 0.f;
        for (int k = j; k < V; k += 8) {
            float e = __expf(s[vq * 65 + k] - m); s[vq * 65 + k] = e; sum += e;
        }
        for (int off = 1; off < 8; off <<= 1) sum += __shfl_xor(sum, off);
        if (j == 0) rsum[vq] = sum;
    }
    __syncthreads();
    float* ob = osa + b * V * F + h * 16;
    for (int i = t; i < V * DH; i += 512) {
        int vq = i >> 4, d = i & 15;
        const float* sr = s + vq * 65;
        float a = 0.f;
        for (int vk = 0; vk < V; vk++) a += sr[vk] * vh[vk * 17 + d];
        ob[vq * F + d] = a / rsum[vq];
    }
}

// ---------------- proj + residual: feat += o @ wc^T ----------------
__global__ void k_proj_res(const float* __restrict__ ws, const float* __restrict__ oin,
                           float* __restrict__ feat) {
    int bv = blockIdx.x; int t = threadIdx.x;
    __shared__ float orow[128];
    orow[t] = oin[bv * F + t];
    __syncthreads();
    const float* wcT = ws + WCSA_T;
    float a = 0.f;
    for (int k = 0; k < 128; k++) a += orow[k] * wcT[k * 128 + t];
    feat[bv * F + t] += a;
}

// ---------------- LaneAttentionFut, block per (b,h), 512 thr ----------------
__global__ __launch_bounds__(512) void k_laf(const float* __restrict__ ws,
                                             const float* __restrict__ feat,
                                             float* __restrict__ ola) {
    int bh = blockIdx.x; int b = bh >> 3, h = bh & 7;
    int t = threadIdx.x;                // 0..511
    __shared__ float xs[64 * 129];
    __shared__ float qh[64 * 17];
    __shared__ float kh[128 * 17], vh[128 * 17];
    __shared__ float s[64 * 129];
    __shared__ float rsum[64];
    const float* fb = feat + b * V * F;
    for (int i = t; i < V * F; i += 512) xs[(i >> 7) * 129 + (i & 127)] = fb[i];
    const float* kb = ws + OFF_KLF + b * NL * F + h * 16;
    const float* vb = ws + OFF_VLF + b * NL * F + h * 16;
    for (int i = t; i < NL * DH; i += 512) {
        int l = i >> 4, d = i & 15;
        kh[l * 17 + d] = kb[l * F + d];
        vh[l * 17 + d] = vb[l * F + d];
    }
    __syncthreads();
    const float* wqT = ws + WQLA_T + h * 16;
    for (int i = t; i < V * DH; i += 512) {
        int v = i >> 4, d = i & 15;
        const float* xr = xs + v * 129;
        float a = 0.f;
        for (int k = 0; k < 128; k++) a += xr[k] * wqT[k * 128 + d];
        qh[v * 17 + d] = a;
    }
    __syncthreads();
    for (int i = t; i < V * NL; i += 512) {
        int vq = i >> 7, l = i & 127;
        const float* qr = qh + vq * 17; const float* kr = kh + l * 17;
        float a = 0.f;
        for (int d = 0; d < 16; d++) a += qr[d] * kr[d];
        s[vq * 129 + l] = a * 0.25f;
    }
    __syncthreads();
    {
        int vq = t >> 3, j = t & 7;
        float m = -1e30f;
        for (int k = j; k < NL; k += 8) m = fmaxf(m, s[vq * 129 + k]);
        for (int off = 1; off < 8; off <<= 1) m = fmaxf(m, __shfl_xor(m, off));
        float sum = 0.f;
        for (int k = j; k < NL; k += 8) {
            float e = __expf(s[vq * 129 + k] - m); s[vq * 129 + k] = e; sum += e;
        }
        for (int off = 1; off < 8; off <<= 1) sum += __shfl_xor(sum, off);
        if (j == 0) rsum[vq] = sum;
    }
    __syncthreads();
    float* ob = ola + b * V * F + h * 16;
    for (int i = t; i < V * DH; i += 512) {
        int vq = i >> 4, d = i & 15;
        const float* sr = s + vq * 129;
        float a = 0.f;
        for (int l = 0; l < NL; l++) a += sr[l] * vh[l * 17 + d];
        ob[vq * F + d] = a / rsum[vq];
    }
}

// ---------------- final proj + residual + MLP + activation + T-broadcast ----------------
__global__ void k_out(const float* __restrict__ ws, const float* __restrict__ ola,
                      const float* __restrict__ feat, const int* __restrict__ flag,
                      void* __restrict__ out) {
    int bv = blockIdx.x; int t = threadIdx.x;   // 128 thr
    __shared__ float orow[128], h3[128], z1[128], z2[128], z3[36], act36[36];
    orow[t] = ola[bv * F + t];
    __syncthreads();
    const float* wclaT = ws + WCLA_T;
    float a = 0.f;
    for (int k = 0; k < 128; k++) a += orow[k] * wclaT[k * 128 + t];
    h3[t] = a + feat[bv * F + t];
    __syncthreads();
    const float* w1T = ws + W1_T;
    a = ws[OFF_B1 + t];
    for (int k = 0; k < 128; k++) a += h3[k] * w1T[k * 128 + t];
    z1[t] = fmaxf(a, 0.f);
    __syncthreads();
    const float* w2T = ws + W2_T;
    a = ws[OFF_B2 + t];
    for (int k = 0; k < 128; k++) a += z1[k] * w2T[k * 128 + t];
    z2[t] = fmaxf(a, 0.f);
    __syncthreads();
    const float* woT = ws + WO_T;
    if (t < 36) {
        a = ws[OFF_BO + t];
        for (int k = 0; k < 128; k++) a += z2[k] * woT[k * 36 + t];
        z3[t] = a;
    }
    __syncthreads();
    if (t < 36) {
        int c = t % 6;
        float xv = z3[t];
        float r;
        if (c == 0)      r = xv + ws[OFF_POS + bv * 2 + 0];
        else if (c == 1) r = xv + ws[OFF_POS + bv * 2 + 1];
        else if (c == 2 || c == 3) r = __expf(0.5f * xv);
        else if (c == 4) r = tanhf(xv);
        else {
            const float inv = 0.4082482904638631f;  // 1/sqrt(6)
            float m = -1e30f;
            for (int pp = 0; pp < 6; pp++) m = fmaxf(m, z3[pp * 6 + 5] * inv);
            float sum = 0.f;
            for (int pp = 0; pp < 6; pp++) sum += __expf(z3[pp * 6 + 5] * inv - m);
            r = __expf(xv * inv - m) / sum;
        }
        act36[t] = r;
    }
    __syncthreads();
    int fl = *flag;
    if (fl) {
        float* o = (float*)out;
        for (int i = t; i < LEN_PRED * 36; i += 128) {
            int tt = i / 36, c = i - tt * 36;
            o[tt * (B * V * 36) + bv * 36 + c] = act36[c];
        }
    } else {
        bf16* o = (bf16*)out;
        for (int i = t; i < LEN_PRED * 36; i += 128) {
            int tt = i / 36, c = i - tt * 36;
            o[tt * (B * V * 36) + bv * 36 + c] = __float2bfloat16(act36[c]);
        }
    }
}

extern "C" void kernel_launch(void* const* d_in, const int* in_sizes, int n_in,
                              void* d_out, int out_size, void* d_ws, size_t ws_size,
                              hipStream_t stream) {
    float* ws = (float*)d_ws;
    float* feat = ws + OFF_FEAT;
    float* osa  = ws + OFF_OSA;
    int*   flag = (int*)(ws + OFF_FLAG);

    k_detect<<<1, 64, 0, stream>>>(d_in[1], flag);

    InPtrs ptrs;
    for (int i = 0; i < 23; i++) ptrs.p[i] = d_in[i];
    k_prep<<<dim3(1024, 23), 256, 0, stream>>>(ptrs, flag, ws);

    k_laneproj<<<B * NL, 128, 0, stream>>>(ws, ws);
    k_lap<<<B * V, 128, 0, stream>>>(ws, feat);
    k_saf<<<B * H, 512, 0, stream>>>(ws, feat, osa);
    k_proj_res<<<B * V, 128, 0, stream>>>(ws, osa, feat);
    k_laf<<<B * H, 512, 0, stream>>>(ws, feat, osa);
    k_out<<<B * V, 128, 0, stream>>>(ws, osa, feat, flag, d_out);
}

// Round 4
// 130.644 us; speedup vs baseline: 2.4910x; 1.4046x over previous
//
#include <hip/hip_runtime.h>
#include <hip/hip_bf16.h>
#include <math.h>

typedef __hip_bfloat16 bf16;

#define B 32
#define V 64
#define F 128
#define NL 128
#define H 8
#define DH 16
#define LEN_PRED 30

// ---- f32 workspace layout (element offsets) ----
#define OFF_INP   0
#define OFF_LANES 81920
#define OFF_POS   344064
#define OFF_EMBW  348160
#define OFF_EMBB  348928
#define OFF_B1    349056
#define OFF_B2    349184
#define OFF_BO    349312
// transposed weights [in][out]
#define WQP_T     349440
#define WKLP_T    365824
#define WVLP_T    374016
#define WCP_T     382208
#define WKF_T     398592
#define WQSA_T    414976
#define WVF_T     431360
#define WCSA_T    447744
#define WKLF_T    464128
#define WVLF_T    472320
#define WQLA_T    480512
#define WCLA_T    496896
#define W1_T      513280
#define W2_T      529664
#define WO_T      546048
// intermediates
#define OFF_FEAT  550656
#define OFF_OSA   812800

struct InPtrs { const void* p[23]; };

// inline dtype detect: f32 data read as u16 pairs has wild exponents in the
// mantissa halves; bf16 N(0,1) never does. All waves read the same 256 u16
// -> identical result in every wave, no sync needed.
__device__ __forceinline__ int detect_f32(const void* lanesraw, int t) {
    const unsigned short* u = (const unsigned short*)lanesraw;
    int lane = t & 63;
    int wild = 0;
    for (int j = 0; j < 4; j++) {
        int e = (u[lane * 4 + j] >> 7) & 0xFF;
        if (e != 0 && (e < 90 || e > 164)) wild++;
    }
    unsigned long long m = __ballot(wild > 0);
    return (__popcll(m) >= 16) ? 1 : 0;
}

// ---------------- convert to f32; transpose weight matrices [O][K]->[K][O] ----------------
__global__ void k_prep(InPtrs ptrs, float* __restrict__ ws) {
    const int sz[23]   = {81920,262144,4096,768,128, 16384,8192,8192,16384,
                          16384,16384,16384,16384, 8192,8192,16384,16384,
                          16384,128,16384,128,4608,36};
    const int dsto[23] = {OFF_INP,OFF_LANES,OFF_POS,OFF_EMBW,OFF_EMBB,
                          WQP_T,WKLP_T,WVLP_T,WCP_T, WKF_T,WQSA_T,WVF_T,WCSA_T,
                          WKLF_T,WVLF_T,WQLA_T,WCLA_T, W1_T,OFF_B1,W2_T,OFF_B2,
                          WO_T,OFF_BO};
    const int Otab[23] = {0,0,0,0,0, 128,128,128,128, 128,128,128,128,
                          128,128,128,128, 128,0,128,0,36,0};
    const int Ktab[23] = {0,0,0,0,0, 128,64,64,128, 128,128,128,128,
                          64,64,128,128, 128,0,128,0,128,0};
    int t = threadIdx.x;
    int fl = detect_f32(ptrs.p[1], t);
    int seg = blockIdx.y;
    int n = sz[seg], O = Otab[seg], K = Ktab[seg];
    if (O == 0) {                       // linear copy, grid-stride
        for (int i = blockIdx.x * 256 + t; i < n; i += 64 * 256) {
            float v = fl ? ((const float*)ptrs.p[seg])[i]
                         : __bfloat162float(((const bf16*)ptrs.p[seg])[i]);
            ws[dsto[seg] + i] = v;
        }
        return;
    }
    if (blockIdx.x != 0) return;        // one block per matrix
    __shared__ float tile[128 * 129];
    int Kp = K + 1;
    for (int i = t; i < n; i += 256) {
        float v = fl ? ((const float*)ptrs.p[seg])[i]
                     : __bfloat162float(((const bf16*)ptrs.p[seg])[i]);
        int o = i / K, k = i - o * K;
        tile[o * Kp + k] = v;
    }
    __syncthreads();
    float* dst = ws + dsto[seg];
    for (int j = t; j < n; j += 256) {
        int k = j / O, o = j - k * O;
        dst[j] = tile[o * Kp + k];
    }
}

// ---------------- generic lane attention, block per (b,h), 512 thr ----------------
// x (64x128) = embedding (use_emb) or feat; K/V (128x16) computed in-block
// from lanes[b] with transposed 64x128 weights; writes osa[b,v,h*16+d].
__global__ __launch_bounds__(512) void k_attn_lane(
        const float* __restrict__ ws, const float* __restrict__ xsrc, int use_emb,
        int wq_off, int wk_off, int wv_off, float* __restrict__ osa) {
    int bh = blockIdx.x; int b = bh >> 3, h = bh & 7;
    int t = threadIdx.x;                // 0..511
    __shared__ float xs[64 * 129];      // x tile
    __shared__ float u[8448];           // lanes[128][66] then scores[64][132]
    __shared__ float kh[128 * 17], vh[128 * 17], qh[64 * 17];
    __shared__ float rsum[64];
    __shared__ float in4[64 * 4];
    // stage lanes[b]: 128 x 64
    const float* lb = ws + OFF_LANES + b * NL * 64;
    for (int i = t; i < NL * 64; i += 512) u[(i >> 6) * 66 + (i & 63)] = lb[i];
    // stage x
    if (use_emb) {
        if (t < 64) {
            const float* inp = ws + OFF_INP;
            in4[t * 4 + 0] = inp[((b * 2 + 0) * 64 + t) * 20 + 18];
            in4[t * 4 + 1] = inp[((b * 2 + 0) * 64 + t) * 20 + 19];
            in4[t * 4 + 2] = inp[((b * 2 + 1) * 64 + t) * 20 + 18];
            in4[t * 4 + 3] = inp[((b * 2 + 1) * 64 + t) * 20 + 19];
        }
        __syncthreads();
        const float* ew = ws + OFF_EMBW;
        for (int i = t; i < 64 * 128; i += 512) {
            int v = i >> 7, c = i & 127;
            xs[v * 129 + c] = ws[OFF_EMBB + c]
                + in4[v * 4 + 0] * ew[c * 6 + 0] + in4[v * 4 + 1] * ew[c * 6 + 1]
                + in4[v * 4 + 2] * ew[c * 6 + 3] + in4[v * 4 + 3] * ew[c * 6 + 4];
        }
    } else {
        const float* fb = xsrc + b * V * F;
        for (int i = t; i < 64 * 128; i += 512) xs[(i >> 7) * 129 + (i & 127)] = fb[i];
    }
    __syncthreads();
    // K,V projections from lanes (K-dim 64)
    const float* wkT = ws + wk_off + h * 16;
    const float* wvT = ws + wv_off + h * 16;
    for (int i = t; i < NL * DH; i += 512) {
        int l = i >> 4, d = i & 15;
        const float* lr = u + l * 66;
        float ak = 0.f, av = 0.f;
        for (int k = 0; k < 64; k++) {
            float x = lr[k];
            ak += x * wkT[k * 128 + d];
            av += x * wvT[k * 128 + d];
        }
        kh[l * 17 + d] = ak; vh[l * 17 + d] = av;
    }
    // Q projection (K-dim 128)
    const float* wqT = ws + wq_off + h * 16;
    for (int i = t; i < V * DH; i += 512) {
        int v = i >> 4, d = i & 15;
        const float* xr = xs + v * 129;
        float a = 0.f;
        for (int k = 0; k < 128; k++) a += xr[k] * wqT[k * 128 + d];
        qh[v * 17 + d] = a;
    }
    __syncthreads();                    // kh/vh/qh ready, lane reads done
    // scores -> s (reuses u), row stride 132
    float* s = u;
    for (int i = t; i < V * NL; i += 512) {
        int v = i >> 7, l = i & 127;
        const float* qr = qh + v * 17; const float* kr = kh + l * 17;
        float a = 0.f;
        for (int d = 0; d < 16; d++) a += qr[d] * kr[d];
        s[v * 132 + l] = a * 0.25f;
    }
    __syncthreads();
    {   // softmax, 8 lanes per row
        int v = t >> 3, j = t & 7;
        float* sr = s + v * 132;
        float m = -1e30f;
        for (int k = j; k < NL; k += 8) m = fmaxf(m, sr[k]);
        for (int off = 1; off < 8; off <<= 1) m = fmaxf(m, __shfl_xor(m, off));
        float sum = 0.f;
        for (int k = j; k < NL; k += 8) { float e = __expf(sr[k] - m); sr[k] = e; sum += e; }
        for (int off = 1; off < 8; off <<= 1) sum += __shfl_xor(sum, off);
        if (j == 0) rsum[v] = sum;
    }
    __syncthreads();
    // PV + write
    float* ob = osa + b * V * F + h * 16;
    for (int i = t; i < V * DH; i += 512) {
        int v = i >> 4, d = i & 15;
        const float* sr = s + v * 132;
        float a = 0.f;
        for (int l = 0; l < NL; l++) a += sr[l] * vh[l * 17 + d];
        ob[v * F + d] = a / rsum[v];
    }
}

// ---------------- SelfAttentionFut, block per (b,h), 512 thr ----------------
__global__ __launch_bounds__(512) void k_saf(const float* __restrict__ ws,
                                             const float* __restrict__ feat,
                                             float* __restrict__ osa) {
    int bh = blockIdx.x; int b = bh >> 3, h = bh & 7;
    int t = threadIdx.x;
    __shared__ float xs[64 * 129];
    __shared__ float qh[64 * 17], kh[64 * 17], vh[64 * 17];
    __shared__ float s[64 * 68];
    __shared__ float rsum[64];
    const float* fb = feat + b * V * F;
    for (int i = t; i < V * F; i += 512) xs[(i >> 7) * 129 + (i & 127)] = fb[i];
    __syncthreads();
    const float* wkT = ws + WKF_T  + h * 16;
    const float* wqT = ws + WQSA_T + h * 16;
    const float* wvT = ws + WVF_T  + h * 16;
    for (int i = t; i < V * DH; i += 512) {
        int v = i >> 4, d = i & 15;
        const float* xr = xs + v * 129;
        float aq = 0.f, ak = 0.f, av = 0.f;
        for (int k = 0; k < 128; k++) {
            float xv = xr[k];
            aq += xv * wqT[k * 128 + d];
            ak += xv * wkT[k * 128 + d];
            av += xv * wvT[k * 128 + d];
        }
        qh[v * 17 + d] = aq; kh[v * 17 + d] = ak; vh[v * 17 + d] = av;
    }
    __syncthreads();
    for (int i = t; i < V * V; i += 512) {
        int vq = i >> 6, vk = i & 63;
        const float* qr = qh + vq * 17; const float* kr = kh + vk * 17;
        float a = 0.f;
        for (int d = 0; d < 16; d++) a += qr[d] * kr[d];
        s[vq * 68 + vk] = a * 0.25f;
    }
    __syncthreads();
    {
        int vq = t >> 3, j = t & 7;
        float* sr = s + vq * 68;
        float m = -1e30f;
        for (int k = j; k < V; k += 8) m = fmaxf(m, sr[k]);
        for (int off = 1; off < 8; off <<= 1) m = fmaxf(m, __shfl_xor(m, off));
        float sum = 0.f;
        for (int k = j; k < V; k += 8) { float e = __expf(sr[k] - m); sr[k] = e; sum += e; }
        for (int off = 1; off < 8; off <<= 1) sum += __shfl_xor(sum, off);
        if (j == 0) rsum[vq] = sum;
    }
    __syncthreads();
    float* ob = osa + b * V * F + h * 16;
    for (int i = t; i < V * DH; i += 512) {
        int v = i >> 4, d = i & 15;
        const float* sr = s + v * 68;
        float a = 0.f;
        for (int vk = 0; vk < V; vk++) a += sr[vk] * vh[vk * 17 + d];
        ob[v * F + d] = a / rsum[v];
    }
}

// ---------------- proj + residual: feat = osa @ wcT + res ----------------
// mode 0: res = embedding (recomputed inline); mode 1: res = feat (in place)
__global__ void k_projres(const float* __restrict__ ws, const float* __restrict__ osa,
                          int wc_off, int mode, float* __restrict__ feat) {
    int bv = blockIdx.x; int t = threadIdx.x;   // 128 thr
    __shared__ float orow[128];
    orow[t] = osa[bv * F + t];
    __syncthreads();
    const float* wcT = ws + wc_off;
    float a = 0.f;
    for (int k = 0; k < 128; k++) a += orow[k] * wcT[k * 128 + t];
    float res;
    if (mode == 0) {
        int b = bv >> 6, v = bv & 63;
        const float* inp = ws + OFF_INP;
        float i00 = inp[((b * 2 + 0) * 64 + v) * 20 + 18];
        float i01 = inp[((b * 2 + 0) * 64 + v) * 20 + 19];
        float i10 = inp[((b * 2 + 1) * 64 + v) * 20 + 18];
        float i11 = inp[((b * 2 + 1) * 64 + v) * 20 + 19];
        const float* ew = ws + OFF_EMBW;
        res = ws[OFF_EMBB + t] + i00 * ew[t * 6 + 0] + i01 * ew[t * 6 + 1]
            + i10 * ew[t * 6 + 3] + i11 * ew[t * 6 + 4];
    } else {
        res = feat[bv * F + t];
    }
    feat[bv * F + t] = a + res;
}

// ---------------- final proj + residual + MLP + activation + T-broadcast ----------------
__global__ void k_out(const float* __restrict__ ws, const float* __restrict__ ola,
                      const float* __restrict__ feat, const void* __restrict__ lanesraw,
                      void* __restrict__ out) {
    int bv = blockIdx.x; int t = threadIdx.x;   // 128 thr
    int fl = detect_f32(lanesraw, t);
    __shared__ float orow[128], h3[128], z1[128], z2[128], z3[36], act36[36];
    orow[t] = ola[bv * F + t];
    __syncthreads();
    const float* wclaT = ws + WCLA_T;
    float a = 0.f;
    for (int k = 0; k < 128; k++) a += orow[k] * wclaT[k * 128 + t];
    h3[t] = a + feat[bv * F + t];
    __syncthreads();
    const float* w1T = ws + W1_T;
    a = ws[OFF_B1 + t];
    for (int k = 0; k < 128; k++) a += h3[k] * w1T[k * 128 + t];
    z1[t] = fmaxf(a, 0.f);
    __syncthreads();
    const float* w2T = ws + W2_T;
    a = ws[OFF_B2 + t];
    for (int k = 0; k < 128; k++) a += z1[k] * w2T[k * 128 + t];
    z2[t] = fmaxf(a, 0.f);
    __syncthreads();
    const float* woT = ws + WO_T;
    if (t < 36) {
        a = ws[OFF_BO + t];
        for (int k = 0; k < 128; k++) a += z2[k] * woT[k * 36 + t];
        z3[t] = a;
    }
    __syncthreads();
    if (t < 36) {
        int c = t % 6;
        float xv = z3[t];
        float r;
        if (c == 0)      r = xv + ws[OFF_POS + bv * 2 + 0];
        else if (c == 1) r = xv + ws[OFF_POS + bv * 2 + 1];
        else if (c == 2 || c == 3) r = __expf(0.5f * xv);
        else if (c == 4) r = tanhf(xv);
        else {
            const float inv = 0.4082482904638631f;  // 1/sqrt(6)
            float m = -1e30f;
            for (int pp = 0; pp < 6; pp++) m = fmaxf(m, z3[pp * 6 + 5] * inv);
            float sum = 0.f;
            for (int pp = 0; pp < 6; pp++) sum += __expf(z3[pp * 6 + 5] * inv - m);
            r = __expf(xv * inv - m) / sum;
        }
        act36[t] = r;
    }
    __syncthreads();
    if (fl) {
        float* o = (float*)out;
        for (int i = t; i < LEN_PRED * 36; i += 128) {
            int tt = i / 36, c = i - tt * 36;
            o[tt * (B * V * 36) + bv * 36 + c] = act36[c];
        }
    } else {
        bf16* o = (bf16*)out;
        for (int i = t; i < LEN_PRED * 36; i += 128) {
            int tt = i / 36, c = i - tt * 36;
            o[tt * (B * V * 36) + bv * 36 + c] = __float2bfloat16(act36[c]);
        }
    }
}

extern "C" void kernel_launch(void* const* d_in, const int* in_sizes, int n_in,
                              void* d_out, int out_size, void* d_ws, size_t ws_size,
                              hipStream_t stream) {
    float* ws   = (float*)d_ws;
    float* feat = ws + OFF_FEAT;
    float* osa  = ws + OFF_OSA;

    InPtrs ptrs;
    for (int i = 0; i < 23; i++) ptrs.p[i] = d_in[i];
    k_prep<<<dim3(64, 23), 256, 0, stream>>>(ptrs, ws);

    // LaneAttentionPast (x = embedding inline)
    k_attn_lane<<<B * H, 512, 0, stream>>>(ws, nullptr, 1, WQP_T, WKLP_T, WVLP_T, osa);
    k_projres<<<B * V, 128, 0, stream>>>(ws, osa, WCP_T, 0, feat);
    // SelfAttentionFut
    k_saf<<<B * H, 512, 0, stream>>>(ws, feat, osa);
    k_projres<<<B * V, 128, 0, stream>>>(ws, osa, WCSA_T, 1, feat);
    // LaneAttentionFut
    k_attn_lane<<<B * H, 512, 0, stream>>>(ws, feat, 0, WQLA_T, WKLF_T, WVLF_T, osa);
    // Output head + broadcast over LEN_PRED
    k_out<<<B * V, 128, 0, stream>>>(ws, osa, feat, d_in[1], d_out);
}

// Round 5
// 118.216 us; speedup vs baseline: 2.7528x; 1.1051x over previous
//
#include <hip/hip_runtime.h>
#include <hip/hip_bf16.h>
#include <math.h>

typedef __hip_bfloat16 bf16;
typedef float4 f4;

#define B 32
#define V 64
#define F 128
#define NL 128
#define H 8
#define DH 16
#define LEN_PRED 30

// ---- f32 workspace layout (element offsets) ----
#define OFF_EMBW 0
#define OFF_EMBB 768
#define OFF_B1   896
#define OFF_B2   1024
#define OFF_BO   1152
#define WCP_T    1216
#define WCSA_T   17600
#define WCLA_T   33984
#define W1_T     50368
#define W2_T     66752
#define WO_T     83136
#define OFF_FEAT 87744
#define OFF_OSA  349888
#define OFF_ACT  612032

struct InPtrs { const void* p[23]; };

// inline dtype detect: f32 data read as u16 pairs has wild exponents in the
// mantissa halves; bf16 N(0,1) never does. Every wave computes the same bit.
__device__ __forceinline__ int detect_f32(const void* lanesraw, int t) {
    const unsigned short* u = (const unsigned short*)lanesraw;
    int lane = t & 63;
    int wild = 0;
    for (int j = 0; j < 4; j++) {
        int e = (u[lane * 4 + j] >> 7) & 0xFF;
        if (e != 0 && (e < 90 || e > 164)) wild++;
    }
    unsigned long long m = __ballot(wild > 0);
    return (__popcll(m) >= 16) ? 1 : 0;
}

__device__ __forceinline__ float ldin(const void* p, int i, int fl) {
    return fl ? ((const float*)p)[i] : __bfloat162float(((const bf16*)p)[i]);
}

// ---------------- prep: small vecs copy + 6 weight transposes ----------------
__global__ void k_prep(InPtrs ptrs, float* __restrict__ ws) {
    // seg: {src_idx, n, dst, O, K}
    const int srci[11] = {3, 4, 18, 20, 22, 8, 12, 16, 17, 19, 21};
    const int szs[11]  = {768, 128, 128, 128, 36, 16384, 16384, 16384, 16384, 16384, 4608};
    const int dsto[11] = {OFF_EMBW, OFF_EMBB, OFF_B1, OFF_B2, OFF_BO,
                          WCP_T, WCSA_T, WCLA_T, W1_T, W2_T, WO_T};
    const int Otab[11] = {0, 0, 0, 0, 0, 128, 128, 128, 128, 128, 36};
    int t = threadIdx.x;
    int fl = detect_f32(ptrs.p[1], t);
    int seg = blockIdx.x;
    int n = szs[seg], O = Otab[seg];
    const void* src = ptrs.p[srci[seg]];
    if (O == 0) {
        for (int i = t; i < n; i += 256) ws[dsto[seg] + i] = ldin(src, i, fl);
        return;
    }
    __shared__ float tile[128 * 129];
    const int K = 128, Kp = 129;
    for (int i = t; i < n; i += 256) {
        int o = i / K, k = i - o * K;
        tile[o * Kp + k] = ldin(src, i, fl);
    }
    __syncthreads();
    float* dst = ws + dsto[seg];
    for (int j = t; j < n; j += 256) {
        int k = j / O, o = j - k * O;
        dst[j] = tile[o * Kp + k];
    }
}

// ---------------- lane attention (past & fut), block per (b,h), 512 thr ----------------
__global__ __launch_bounds__(512) void k_attn_lane(
        const void* __restrict__ rw_q, const void* __restrict__ rw_k,
        const void* __restrict__ rw_v, const void* __restrict__ rlanes,
        const void* __restrict__ rinp, const float* __restrict__ ws,
        const float* __restrict__ xsrc, int use_emb, float* __restrict__ osa) {
    int bh = blockIdx.x; int b = bh >> 3, h = bh & 7;
    int t = threadIdx.x;
    int fl = detect_f32(rlanes, t);
    __shared__ __align__(16) float ln[128 * 68];    // lanes; aliased by scores later
    __shared__ __align__(16) float xs[64 * 132];
    __shared__ __align__(16) float wql[16 * 132];
    __shared__ __align__(16) float wkl[16 * 68];
    __shared__ __align__(16) float wvl[16 * 68];
    __shared__ __align__(16) float kh[128 * 20];
    __shared__ __align__(16) float vhT[16 * 132];
    __shared__ __align__(16) float qh[64 * 20];
    __shared__ float rsum[64];
    __shared__ float in4[64 * 4];
    float* s = ln;                                  // scores alias (ln dead after proj)

    // ---- stage ----
    {
        int lb = b * NL * 64;
        for (int i = t; i < NL * 64; i += 512)
            ln[(i >> 6) * 68 + (i & 63)] = ldin(rlanes, lb + i, fl);
        for (int i = t; i < 16 * 128; i += 512)
            wql[(i >> 7) * 132 + (i & 127)] = ldin(rw_q, h * 16 * 128 + i, fl);
        for (int i = t; i < 16 * 64; i += 512)
            wkl[(i >> 6) * 68 + (i & 63)] = ldin(rw_k, h * 16 * 64 + i, fl);
        for (int i = t; i < 16 * 64; i += 512)
            wvl[(i >> 6) * 68 + (i & 63)] = ldin(rw_v, h * 16 * 64 + i, fl);
    }
    if (use_emb) {
        if (t < 64) {
            in4[t * 4 + 0] = ldin(rinp, ((b * 2 + 0) * 64 + t) * 20 + 18, fl);
            in4[t * 4 + 1] = ldin(rinp, ((b * 2 + 0) * 64 + t) * 20 + 19, fl);
            in4[t * 4 + 2] = ldin(rinp, ((b * 2 + 1) * 64 + t) * 20 + 18, fl);
            in4[t * 4 + 3] = ldin(rinp, ((b * 2 + 1) * 64 + t) * 20 + 19, fl);
        }
        __syncthreads();
        const float* ew = ws + OFF_EMBW;
        for (int i = t; i < 8192; i += 512) {
            int v = i >> 7, c = i & 127;
            xs[v * 132 + c] = ws[OFF_EMBB + c]
                + in4[v * 4 + 0] * ew[c * 6 + 0] + in4[v * 4 + 1] * ew[c * 6 + 1]
                + in4[v * 4 + 2] * ew[c * 6 + 3] + in4[v * 4 + 3] * ew[c * 6 + 4];
        }
    } else {
        const float* fb = xsrc + b * V * F;
        for (int i = t; i < 8192; i += 512) xs[(i >> 7) * 132 + (i & 127)] = fb[i];
    }
    __syncthreads();

    // ---- proj: KV (t<128, 4l x 4d tiles) and Q (128<=t<192, 4v x 4d tiles) ----
    if (t < 128) {
        int l0 = t >> 2, d0 = t & 3;
        float ak[4][4] = {}, av[4][4] = {};
        for (int kk = 0; kk < 64; kk += 4) {
            f4 L[4], WK[4], WV[4];
            #pragma unroll
            for (int m = 0; m < 4; m++) L[m] = *(const f4*)&ln[(l0 + 32 * m) * 68 + kk];
            #pragma unroll
            for (int i2 = 0; i2 < 4; i2++) WK[i2] = *(const f4*)&wkl[(d0 + 4 * i2) * 68 + kk];
            #pragma unroll
            for (int i2 = 0; i2 < 4; i2++) WV[i2] = *(const f4*)&wvl[(d0 + 4 * i2) * 68 + kk];
            #pragma unroll
            for (int m = 0; m < 4; m++)
                #pragma unroll
                for (int i2 = 0; i2 < 4; i2++) {
                    ak[m][i2] += L[m].x * WK[i2].x + L[m].y * WK[i2].y
                               + L[m].z * WK[i2].z + L[m].w * WK[i2].w;
                    av[m][i2] += L[m].x * WV[i2].x + L[m].y * WV[i2].y
                               + L[m].z * WV[i2].z + L[m].w * WV[i2].w;
                }
        }
        #pragma unroll
        for (int m = 0; m < 4; m++)
            #pragma unroll
            for (int i2 = 0; i2 < 4; i2++) {
                int l = l0 + 32 * m, d = d0 + 4 * i2;
                kh[l * 20 + d] = ak[m][i2];
                vhT[d * 132 + l] = av[m][i2];
            }
    } else if (t < 192) {
        int tt = t - 128, v0 = tt >> 2, d0 = tt & 3;
        float aq[4][4] = {};
        for (int kk = 0; kk < 128; kk += 4) {
            f4 X[4], WQ[4];
            #pragma unroll
            for (int m = 0; m < 4; m++) X[m] = *(const f4*)&xs[(v0 + 16 * m) * 132 + kk];
            #pragma unroll
            for (int i2 = 0; i2 < 4; i2++) WQ[i2] = *(const f4*)&wql[(d0 + 4 * i2) * 132 + kk];
            #pragma unroll
            for (int m = 0; m < 4; m++)
                #pragma unroll
                for (int i2 = 0; i2 < 4; i2++)
                    aq[m][i2] += X[m].x * WQ[i2].x + X[m].y * WQ[i2].y
                               + X[m].z * WQ[i2].z + X[m].w * WQ[i2].w;
        }
        #pragma unroll
        for (int m = 0; m < 4; m++)
            #pragma unroll
            for (int i2 = 0; i2 < 4; i2++)
                qh[(v0 + 16 * m) * 20 + d0 + 4 * i2] = aq[m][i2];
    }
    __syncthreads();

    // ---- scores: all 512 thr, 4v x 4l tiles ----
    {
        int v0 = t >> 5, l0 = t & 31;
        float sc[4][4] = {};
        #pragma unroll
        for (int kd = 0; kd < 16; kd += 4) {
            f4 Q[4], K4[4];
            #pragma unroll
            for (int m = 0; m < 4; m++) Q[m] = *(const f4*)&qh[(v0 + 16 * m) * 20 + kd];
            #pragma unroll
            for (int i2 = 0; i2 < 4; i2++) K4[i2] = *(const f4*)&kh[(l0 + 32 * i2) * 20 + kd];
            #pragma unroll
            for (int m = 0; m < 4; m++)
                #pragma unroll
                for (int i2 = 0; i2 < 4; i2++)
                    sc[m][i2] += Q[m].x * K4[i2].x + Q[m].y * K4[i2].y
                               + Q[m].z * K4[i2].z + Q[m].w * K4[i2].w;
        }
        #pragma unroll
        for (int m = 0; m < 4; m++)
            #pragma unroll
            for (int i2 = 0; i2 < 4; i2++)
                s[(v0 + 16 * m) * 132 + l0 + 32 * i2] = sc[m][i2] * 0.25f;
    }
    __syncthreads();

    // ---- softmax: 8 lanes per row ----
    {
        int v = t >> 3, j = t & 7;
        float* sr = s + v * 132;
        float m = -1e30f;
        for (int k = j; k < NL; k += 8) m = fmaxf(m, sr[k]);
        for (int off = 1; off < 8; off <<= 1) m = fmaxf(m, __shfl_xor(m, off));
        float sum = 0.f;
        for (int k = j; k < NL; k += 8) { float e = __expf(sr[k] - m); sr[k] = e; sum += e; }
        for (int off = 1; off < 8; off <<= 1) sum += __shfl_xor(sum, off);
        if (j == 0) rsum[v] = sum;
    }
    __syncthreads();

    // ---- PV: t<64, 4v x 4d tiles over l ----
    if (t < 64) {
        int v0 = t >> 2, d0 = t & 3;
        float o4[4][4] = {};
        for (int ll = 0; ll < NL; ll += 4) {
            f4 S4[4], VT[4];
            #pragma unroll
            for (int m = 0; m < 4; m++) S4[m] = *(const f4*)&s[(v0 + 16 * m) * 132 + ll];
            #pragma unroll
            for (int i2 = 0; i2 < 4; i2++) VT[i2] = *(const f4*)&vhT[(d0 + 4 * i2) * 132 + ll];
            #pragma unroll
            for (int m = 0; m < 4; m++)
                #pragma unroll
                for (int i2 = 0; i2 < 4; i2++)
                    o4[m][i2] += S4[m].x * VT[i2].x + S4[m].y * VT[i2].y
                               + S4[m].z * VT[i2].z + S4[m].w * VT[i2].w;
        }
        float* ob = osa + b * V * F + h * 16;
        #pragma unroll
        for (int m = 0; m < 4; m++) {
            int v = v0 + 16 * m;
            #pragma unroll
            for (int i2 = 0; i2 < 4; i2++)
                ob[v * F + d0 + 4 * i2] = o4[m][i2] / rsum[v];
        }
    }
}

// ---------------- SelfAttentionFut, block per (b,h), 512 thr ----------------
__global__ __launch_bounds__(512) void k_saf(
        const void* __restrict__ rw_q, const void* __restrict__ rw_k,
        const void* __restrict__ rw_v, const void* __restrict__ rlanes,
        const float* __restrict__ feat, float* __restrict__ osa) {
    int bh = blockIdx.x; int b = bh >> 3, h = bh & 7;
    int t = threadIdx.x;
    int fl = detect_f32(rlanes, t);
    __shared__ __align__(16) float xs[64 * 132];
    __shared__ __align__(16) float wsl[3 * 16 * 132];   // q,k,v head slices
    __shared__ __align__(16) float qh[64 * 20], kh[64 * 20];
    __shared__ __align__(16) float vhT[16 * 68];
    __shared__ __align__(16) float s2[64 * 68];
    __shared__ float rsum[64];

    const float* fb = feat + b * V * F;
    for (int i = t; i < 8192; i += 512) xs[(i >> 7) * 132 + (i & 127)] = fb[i];
    for (int i = t; i < 16 * 128; i += 512) {
        wsl[0 * 2112 + (i >> 7) * 132 + (i & 127)] = ldin(rw_q, h * 16 * 128 + i, fl);
        wsl[1 * 2112 + (i >> 7) * 132 + (i & 127)] = ldin(rw_k, h * 16 * 128 + i, fl);
        wsl[2 * 2112 + (i >> 7) * 132 + (i & 127)] = ldin(rw_v, h * 16 * 128 + i, fl);
    }
    __syncthreads();

    // ---- proj q/k/v: t<192, one mat per 64-thread group, 4v x 4d tiles ----
    if (t < 192) {
        int mat = t >> 6, tt = t & 63, v0 = tt >> 2, d0 = tt & 3;
        const float* wm = wsl + mat * 2112;
        float ac[4][4] = {};
        for (int kk = 0; kk < 128; kk += 4) {
            f4 X[4], W[4];
            #pragma unroll
            for (int m = 0; m < 4; m++) X[m] = *(const f4*)&xs[(v0 + 16 * m) * 132 + kk];
            #pragma unroll
            for (int i2 = 0; i2 < 4; i2++) W[i2] = *(const f4*)&wm[(d0 + 4 * i2) * 132 + kk];
            #pragma unroll
            for (int m = 0; m < 4; m++)
                #pragma unroll
                for (int i2 = 0; i2 < 4; i2++)
                    ac[m][i2] += X[m].x * W[i2].x + X[m].y * W[i2].y
                               + X[m].z * W[i2].z + X[m].w * W[i2].w;
        }
        #pragma unroll
        for (int m = 0; m < 4; m++)
            #pragma unroll
            for (int i2 = 0; i2 < 4; i2++) {
                int v = v0 + 16 * m, d = d0 + 4 * i2;
                if (mat == 0) qh[v * 20 + d] = ac[m][i2];
                else if (mat == 1) kh[v * 20 + d] = ac[m][i2];
                else vhT[d * 68 + v] = ac[m][i2];
            }
    }
    __syncthreads();

    // ---- scores 64x64: t<256, 4v x 4l tiles ----
    if (t < 256) {
        int v0 = t >> 4, l0 = t & 15;
        float sc[4][4] = {};
        #pragma unroll
        for (int kd = 0; kd < 16; kd += 4) {
            f4 Q[4], K4[4];
            #pragma unroll
            for (int m = 0; m < 4; m++) Q[m] = *(const f4*)&qh[(v0 + 16 * m) * 20 + kd];
            #pragma unroll
            for (int i2 = 0; i2 < 4; i2++) K4[i2] = *(const f4*)&kh[(l0 + 16 * i2) * 20 + kd];
            #pragma unroll
            for (int m = 0; m < 4; m++)
                #pragma unroll
                for (int i2 = 0; i2 < 4; i2++)
                    sc[m][i2] += Q[m].x * K4[i2].x + Q[m].y * K4[i2].y
                               + Q[m].z * K4[i2].z + Q[m].w * K4[i2].w;
        }
        #pragma unroll
        for (int m = 0; m < 4; m++)
            #pragma unroll
            for (int i2 = 0; i2 < 4; i2++)
                s2[(v0 + 16 * m) * 68 + l0 + 16 * i2] = sc[m][i2] * 0.25f;
    }
    __syncthreads();

    // ---- softmax ----
    {
        int v = t >> 3, j = t & 7;
        float* sr = s2 + v * 68;
        float m = -1e30f;
        for (int k = j; k < V; k += 8) m = fmaxf(m, sr[k]);
        for (int off = 1; off < 8; off <<= 1) m = fmaxf(m, __shfl_xor(m, off));
        float sum = 0.f;
        for (int k = j; k < V; k += 8) { float e = __expf(sr[k] - m); sr[k] = e; sum += e; }
        for (int off = 1; off < 8; off <<= 1) sum += __shfl_xor(sum, off);
        if (j == 0) rsum[v] = sum;
    }
    __syncthreads();

    // ---- PV: t<64, 4v x 4d over vk ----
    if (t < 64) {
        int v0 = t >> 2, d0 = t & 3;
        float o4[4][4] = {};
        for (int ll = 0; ll < V; ll += 4) {
            f4 S4[4], VT[4];
            #pragma unroll
            for (int m = 0; m < 4; m++) S4[m] = *(const f4*)&s2[(v0 + 16 * m) * 68 + ll];
            #pragma unroll
            for (int i2 = 0; i2 < 4; i2++) VT[i2] = *(const f4*)&vhT[(d0 + 4 * i2) * 68 + ll];
            #pragma unroll
            for (int m = 0; m < 4; m++)
                #pragma unroll
                for (int i2 = 0; i2 < 4; i2++)
                    o4[m][i2] += S4[m].x * VT[i2].x + S4[m].y * VT[i2].y
                               + S4[m].z * VT[i2].z + S4[m].w * VT[i2].w;
        }
        float* ob = osa + b * V * F + h * 16;
        #pragma unroll
        for (int m = 0; m < 4; m++) {
            int v = v0 + 16 * m;
            #pragma unroll
            for (int i2 = 0; i2 < 4; i2++)
                ob[v * F + d0 + 4 * i2] = o4[m][i2] / rsum[v];
        }
    }
}

// ---------------- proj + residual: feat = osa @ wcT + res ----------------
__global__ void k_projres(const float* __restrict__ ws, const float* __restrict__ osa,
                          const void* __restrict__ rinp, const void* __restrict__ rlanes,
                          int wc_off, int mode, float* __restrict__ feat) {
    int bv = blockIdx.x; int t = threadIdx.x;   // 128 thr
    __shared__ float orow[128];
    orow[t] = osa[bv * F + t];
    __syncthreads();
    const float* wcT = ws + wc_off;
    float a = 0.f;
    for (int k = 0; k < 128; k++) a += orow[k] * wcT[k * 128 + t];
    float res;
    if (mode == 0) {
        int fl = detect_f32(rlanes, t);
        int b = bv >> 6, v = bv & 63;
        float i00 = ldin(rinp, ((b * 2 + 0) * 64 + v) * 20 + 18, fl);
        float i01 = ldin(rinp, ((b * 2 + 0) * 64 + v) * 20 + 19, fl);
        float i10 = ldin(rinp, ((b * 2 + 1) * 64 + v) * 20 + 18, fl);
        float i11 = ldin(rinp, ((b * 2 + 1) * 64 + v) * 20 + 19, fl);
        const float* ew = ws + OFF_EMBW;
        res = ws[OFF_EMBB + t] + i00 * ew[t * 6 + 0] + i01 * ew[t * 6 + 1]
            + i10 * ew[t * 6 + 3] + i11 * ew[t * 6 + 4];
    } else {
        res = feat[bv * F + t];
    }
    feat[bv * F + t] = a + res;
}

// ---------------- final proj + residual + MLP + activation -> act ----------------
__global__ void k_out(const float* __restrict__ ws, const float* __restrict__ ola,
                      const float* __restrict__ feat, const void* __restrict__ rpos,
                      const void* __restrict__ rlanes, float* __restrict__ act) {
    int bv = blockIdx.x; int t = threadIdx.x;   // 128 thr
    __shared__ float orow[128], h3[128], z1[128], z2[128], z3[36];
    orow[t] = ola[bv * F + t];
    __syncthreads();
    const float* wclaT = ws + WCLA_T;
    float a = 0.f;
    for (int k = 0; k < 128; k++) a += orow[k] * wclaT[k * 128 + t];
    h3[t] = a + feat[bv * F + t];
    __syncthreads();
    const float* w1T = ws + W1_T;
    a = ws[OFF_B1 + t];
    for (int k = 0; k < 128; k++) a += h3[k] * w1T[k * 128 + t];
    z1[t] = fmaxf(a, 0.f);
    __syncthreads();
    const float* w2T = ws + W2_T;
    a = ws[OFF_B2 + t];
    for (int k = 0; k < 128; k++) a += z1[k] * w2T[k * 128 + t];
    z2[t] = fmaxf(a, 0.f);
    __syncthreads();
    const float* woT = ws + WO_T;
    if (t < 36) {
        a = ws[OFF_BO + t];
        for (int k = 0; k < 128; k++) a += z2[k] * woT[k * 36 + t];
        z3[t] = a;
    }
    __syncthreads();
    if (t < 36) {
        int fl = detect_f32(rlanes, t);  // t<36 subset of one wave; uniform result still
        int c = t % 6;
        float xv = z3[t];
        float r;
        if (c == 0)      r = xv + ldin(rpos, bv * 2 + 0, fl);
        else if (c == 1) r = xv + ldin(rpos, bv * 2 + 1, fl);
        else if (c == 2 || c == 3) r = __expf(0.5f * xv);
        else if (c == 4) r = tanhf(xv);
        else {
            const float inv = 0.4082482904638631f;  // 1/sqrt(6)
            float m = -1e30f;
            for (int pp = 0; pp < 6; pp++) m = fmaxf(m, z3[pp * 6 + 5] * inv);
            float sum = 0.f;
            for (int pp = 0; pp < 6; pp++) sum += __expf(z3[pp * 6 + 5] * inv - m);
            r = __expf(xv * inv - m) / sum;
        }
        act[bv * 36 + t] = r;
    }
}

// ---------------- broadcast over LEN_PRED, coalesced grid-stride ----------------
__global__ void k_bcast(const float* __restrict__ act, const void* __restrict__ rlanes,
                        void* __restrict__ out) {
    int fl = detect_f32(rlanes, threadIdx.x);
    const int total = LEN_PRED * B * V * 36;
    for (int i = blockIdx.x * 256 + threadIdx.x; i < total; i += 2048 * 256) {
        float v = act[i % (B * V * 36)];
        if (fl) ((float*)out)[i] = v;
        else    ((bf16*)out)[i] = __float2bfloat16(v);
    }
}

extern "C" void kernel_launch(void* const* d_in, const int* in_sizes, int n_in,
                              void* d_out, int out_size, void* d_ws, size_t ws_size,
                              hipStream_t stream) {
    float* ws   = (float*)d_ws;
    float* feat = ws + OFF_FEAT;
    float* osa  = ws + OFF_OSA;
    float* act  = ws + OFF_ACT;

    InPtrs ptrs;
    for (int i = 0; i < 23; i++) ptrs.p[i] = d_in[i];
    k_prep<<<11, 256, 0, stream>>>(ptrs, ws);

    // LaneAttentionPast (x = embedding inline)
    k_attn_lane<<<B * H, 512, 0, stream>>>(d_in[5], d_in[6], d_in[7], d_in[1], d_in[0],
                                           ws, nullptr, 1, osa);
    k_projres<<<B * V, 128, 0, stream>>>(ws, osa, d_in[0], d_in[1], WCP_T, 0, feat);
    // SelfAttentionFut
    k_saf<<<B * H, 512, 0, stream>>>(d_in[10], d_in[9], d_in[11], d_in[1], feat, osa);
    k_projres<<<B * V, 128, 0, stream>>>(ws, osa, d_in[0], d_in[1], WCSA_T, 1, feat);
    // LaneAttentionFut
    k_attn_lane<<<B * H, 512, 0, stream>>>(d_in[15], d_in[13], d_in[14], d_in[1], d_in[0],
                                           ws, feat, 0, osa);
    // Output head + broadcast
    k_out<<<B * V, 128, 0, stream>>>(ws, osa, feat, d_in[2], d_in[1], act);
    k_bcast<<<2048, 256, 0, stream>>>(act, d_in[1], d_out);
}